// Round 8
// baseline (114.203 us; speedup 1.0000x reference)
//
#include <hip/hip_runtime.h>
#include <math.h>

// Cox partial likelihood NLL.
// loss = -(1/n) * sum_i e_i * (risk_i - log(P[time_i]))
//   where P[t] = sum_{t' <= t} S[t'],  S[t] = sum_{time_j = t} exp(risk_j)
//
// R8: ABLATION ROUND. R5 pipeline kept verbatim for correctness (best timed
// 55.2us). Two added probes read the same 192 MB with the same grid/VPT:
//   k1_probe  = loads + exp + accA only          -> streaming floor
//   k1_probe2 = + trailing sums + seg-scan+carry -> scan machinery cost
// (probe results stay live via folded partial stores; no DCE.)
// Next round drops the probes and attacks whichever delta dominates.

#define TMAXV   100000
#define NPAD    100352          // 98 * 1024, padded bucket count
#define NBLK_SC 98
#define VPT     16              // elements per thread per window
#define NBLK1   2048
#define SENT    0x7fffffff      // sentinel time for invalid lanes

__device__ __forceinline__ void atomAddF(float* p, float v) {
    unsafeAtomicAdd(p, v);      // native global_atomic_add_f32
}

// Block reduce (up to 16 waves). Result valid in lane 0 of wave 0 only.
__device__ __forceinline__ float block_reduce_sum(float v, float* lds) {
    const int lane = threadIdx.x & 63;
    const int wid  = threadIdx.x >> 6;
    #pragma unroll
    for (int d = 32; d > 0; d >>= 1) v += __shfl_down(v, d);
    __syncthreads();
    if (lane == 0) lds[wid] = v;
    __syncthreads();
    float r = 0.f;
    if (wid == 0) {
        const int nw = (int)(blockDim.x >> 6);
        r = (lane < nw) ? lds[lane] : 0.f;
        #pragma unroll
        for (int d = 8; d > 0; d >>= 1) r += __shfl_down(r, d);
    }
    return r;
}

// Window load into registers (shared by all K1 variants).
#define LOADWIN(R, W, T)                                                       \
    do {                                                                       \
        if (base + VPT <= end) {                                               \
            _Pragma("unroll")                                                  \
            for (int q = 0; q < VPT / 4; ++q) {                                \
                const float4 rr = *(const float4*)(risk + base + 4 * q);       \
                const float4 ww = *(const float4*)(ev   + base + 4 * q);       \
                const int4   tt = *(const int4*)(tim   + base + 4 * q);        \
                R[4*q+0]=rr.x; R[4*q+1]=rr.y; R[4*q+2]=rr.z; R[4*q+3]=rr.w;    \
                W[4*q+0]=ww.x; W[4*q+1]=ww.y; W[4*q+2]=ww.z; W[4*q+3]=ww.w;    \
                T[4*q+0]=tt.x; T[4*q+1]=tt.y; T[4*q+2]=tt.z; T[4*q+3]=tt.w;    \
            }                                                                  \
        } else {                                                               \
            _Pragma("unroll")                                                  \
            for (int j = 0; j < VPT; ++j) {                                    \
                const int i_ = base + j;                                       \
                const bool ok_ = (i_ < end);                                   \
                R[j] = ok_ ? risk[i_] : 0.f;                                   \
                W[j] = ok_ ? ev[i_]   : 0.f;                                   \
                T[j] = ok_ ? tim[i_]  : SENT;                                  \
            }                                                                  \
        }                                                                      \
    } while (0)

// ---------- PROBE 1: streaming floor (loads + exp + accA) ----------
__global__ __launch_bounds__(256)
void k1_probe(const float* __restrict__ risk, const float* __restrict__ ev,
              const int* __restrict__ tim, float* __restrict__ Ppart,
              int n, int per_block) {
    __shared__ float lds[16];
    const int start = (int)blockIdx.x * per_block;
    int end = start + per_block;
    if (end > n) end = n;
    const int step = 256 * VPT;

    float accA = 0.f, accV = 0.f;
    int   accT = 0;
    for (int i0 = start; i0 < end; i0 += step) {
        const int base = i0 + (int)threadIdx.x * VPT;
        float r[VPT], w[VPT];
        int   t[VPT];
        LOADWIN(r, w, t);
        #pragma unroll
        for (int j = 0; j < VPT; ++j) {
            accV += __expf(r[j]);
            accA += w[j] * r[j];
            accT += t[j];                  // keep t loads live
        }
    }
    const float tot = block_reduce_sum(accA + accV * 1e-15f + (float)accT * 1e-30f, lds);
    if (threadIdx.x == 0) Ppart[blockIdx.x] = tot;
}

// ---------- PROBE 2: + trailing sums + segmented scan + carry ----------
__global__ __launch_bounds__(256)
void k1_probe2(const float* __restrict__ risk, const float* __restrict__ ev,
               const int* __restrict__ tim, float* __restrict__ Ppart,
               int n, int per_block) {
    __shared__ float lds[16];
    const int lane  = threadIdx.x & 63;
    const int start = (int)blockIdx.x * per_block;
    int end = start + per_block;
    if (end > n) end = n;
    const int step = 256 * VPT;

    float accA = 0.f, accV = 0.f;
    for (int i0 = start; i0 < end; i0 += step) {
        const int base = i0 + (int)threadIdx.x * VPT;
        float r[VPT], w[VPT];
        int   t[VPT];
        LOADWIN(r, w, t);

        float ve[VPT];
        #pragma unroll
        for (int j = 0; j < VPT; ++j) {
            ve[j] = __expf(r[j]);
            accA += w[j] * r[j];
        }

        const int head_t = t[0];
        const int tail_t = t[VPT - 1];
        float tsv = 0.f, tsw = 0.f;
        #pragma unroll
        for (int j = 0; j < VPT; ++j) {
            if (t[j] == tail_t) { tsv += ve[j]; tsw += w[j]; }
        }

        float Sv = tsv, Sw = tsw;
        #pragma unroll
        for (int d = 1; d < 64; d <<= 1) {
            const float ov = __shfl_up(Sv, d);
            const float ow = __shfl_up(Sw, d);
            const int   ok = __shfl_up(tail_t, d);
            if (lane >= d && ok == tail_t) { Sv += ov; Sw += ow; }
        }
        float cv = 0.f, cw = 0.f;
        {
            const float pv = __shfl_up(Sv, 1);
            const float pw = __shfl_up(Sw, 1);
            const int   pk = __shfl_up(tail_t, 1);
            if (lane > 0 && pk == head_t) { cv = pv; cw = pw; }
        }
        accV += (Sv + Sw + cv + cw) * 1e-20f;   // keep scan results live
    }
    const float tot = block_reduce_sum(accA + accV, lds);
    if (threadIdx.x == 0) Ppart[blockIdx.x] = tot;
}

// ---------- REAL K1 (R5 verbatim) ----------
__global__ __launch_bounds__(256)
void k1_bucket(const float* __restrict__ risk, const float* __restrict__ ev,
               const int* __restrict__ tim,
               float* __restrict__ S, float* __restrict__ E,
               float* __restrict__ Apart, int n, int per_block) {
    __shared__ float lds[16];
    const int lane  = threadIdx.x & 63;
    const int start = (int)blockIdx.x * per_block;
    int end = start + per_block;
    if (end > n) end = n;
    const int step = 256 * VPT;

    float accA = 0.f;
    for (int i0 = start; i0 < end; i0 += step) {
        const int base = i0 + (int)threadIdx.x * VPT;
        float r[VPT], w[VPT];
        int   t[VPT];
        LOADWIN(r, w, t);

        float ve[VPT];
        #pragma unroll
        for (int j = 0; j < VPT; ++j) {
            ve[j] = __expf(r[j]);
            accA += w[j] * r[j];
        }

        const int head_t = t[0];
        const int tail_t = t[VPT - 1];
        float tsv = 0.f, tsw = 0.f;
        #pragma unroll
        for (int j = 0; j < VPT; ++j) {
            if (t[j] == tail_t) { tsv += ve[j]; tsw += w[j]; }
        }

        float Sv = tsv, Sw = tsw;
        #pragma unroll
        for (int d = 1; d < 64; d <<= 1) {
            const float ov = __shfl_up(Sv, d);
            const float ow = __shfl_up(Sw, d);
            const int   ok = __shfl_up(tail_t, d);
            if (lane >= d && ok == tail_t) { Sv += ov; Sw += ow; }
        }

        float cv = 0.f, cw = 0.f;
        {
            const float pv = __shfl_up(Sv, 1);
            const float pw = __shfl_up(Sw, 1);
            const int   pk = __shfl_up(tail_t, 1);
            if (lane > 0 && pk == head_t) { cv = pv; cw = pw; }
        }

        int   cur_t = head_t;
        float cur_v = cv, cur_w = cw;
        #pragma unroll
        for (int j = 0; j < VPT; ++j) {
            if (t[j] != cur_t) {
                if (cur_t != SENT) {
                    atomAddF(&S[cur_t], cur_v);
                    atomAddF(&E[cur_t], cur_w);
                }
                cur_t = t[j]; cur_v = 0.f; cur_w = 0.f;
            }
            cur_v += ve[j]; cur_w += w[j];
        }
        const int nh = __shfl_down(head_t, 1);
        if ((lane == 63 || nh != tail_t) && cur_t != SENT) {
            atomAddF(&S[cur_t], cur_v);
            atomAddF(&E[cur_t], cur_w);
        }
    }

    const float tot = block_reduce_sum(accA, lds);
    if (threadIdx.x == 0) Apart[blockIdx.x] = tot;
}

// K2: per-1024-chunk partial sums of S.
__global__ __launch_bounds__(256)
void k2_partials(const float* __restrict__ S, float* __restrict__ partials) {
    __shared__ float lds[16];
    const int base = (int)blockIdx.x * 1024;
    float v = 0.f;
    for (int j = (int)threadIdx.x; j < 1024; j += 256) v += S[base + j];
    const float tot = block_reduce_sum(v, lds);
    if (threadIdx.x == 0) partials[blockIdx.x] = tot;
}

// K3: per-chunk inclusive scan of S (+offset), dot with E via log(P) -> B.
__global__ __launch_bounds__(1024)
void k3_scan_dot(const float* __restrict__ S, const float* __restrict__ E,
                 const float* __restrict__ partials, float* __restrict__ Bacc) {
    __shared__ float lds[16];
    __shared__ float wsum[16];
    __shared__ float s_off;
    const int tid  = (int)threadIdx.x;
    const int lane = tid & 63;
    const int wid  = tid >> 6;
    const int base = (int)blockIdx.x * 1024;

    float p = (tid < (int)blockIdx.x) ? partials[tid] : 0.f;
    const float off = block_reduce_sum(p, lds);
    if (tid == 0) s_off = off;
    __syncthreads();
    const float offset = s_off;

    const float x = S[base + tid];
    float s = x;
    #pragma unroll
    for (int d = 1; d < 64; d <<= 1) {
        const float o = __shfl_up(s, d);
        if (lane >= d) s += o;
    }
    if (lane == 63) wsum[wid] = s;
    __syncthreads();
    if (wid == 0) {
        float ws = (lane < 16) ? wsum[lane] : 0.f;
        #pragma unroll
        for (int d = 1; d < 16; d <<= 1) {
            const float o = __shfl_up(ws, d);
            if (lane >= d) ws += o;
        }
        if (lane < 16) wsum[lane] = ws;
    }
    __syncthreads();
    const float incl = s + (wid > 0 ? wsum[wid - 1] : 0.f);
    const float P = offset + incl;

    const float w = E[base + tid];
    const float c = (w != 0.f) ? w * __logf(P) : 0.f;
    const float tot = block_reduce_sum(c, lds);
    if (tid == 0) atomAddF(Bacc, tot);
}

// K4: reduce Apart[NBLK1], combine with B, write loss.
__global__ __launch_bounds__(256)
void k4_final(const float* __restrict__ Apart, const float* __restrict__ B,
              float* __restrict__ out, float inv_n) {
    __shared__ float lds[16];
    float v = 0.f;
    for (int j = (int)threadIdx.x; j < NBLK1; j += 256) v += Apart[j];
    const float tot = block_reduce_sum(v, lds);
    if (threadIdx.x == 0) out[0] = -(tot - B[0]) * inv_n;
}

extern "C" void kernel_launch(void* const* d_in, const int* in_sizes, int n_in,
                              void* d_out, int out_size, void* d_ws, size_t ws_size,
                              hipStream_t stream) {
    const float* risk = (const float*)d_in[0];
    const float* ev   = (const float*)d_in[1];
    const int*   tim  = (const int*)d_in[2];
    float* out = (float*)d_out;
    const int n = in_sizes[0];

    // ws (floats): S[NPAD] E[NPAD] partials[128] Apart[NBLK1] B[2] Pp[NBLK1] Pp2[NBLK1]
    float* S        = (float*)d_ws;
    float* E        = S + NPAD;
    float* partials = E + NPAD;
    float* Apart    = partials + 128;
    float* B        = Apart + NBLK1;
    float* Pp       = B + 2;
    float* Pp2      = Pp + NBLK1;

    hipMemsetAsync(d_ws, 0, (size_t)(2 * NPAD + 128 + NBLK1 + 2) * sizeof(float), stream);

    const int win = 256 * VPT;                         // 4096 elems per window
    int per_block = (n + NBLK1 - 1) / NBLK1;
    per_block = ((per_block + win - 1) / win) * win;   // 8192 for N=16.7M

    hipLaunchKernelGGL(k1_probe,  dim3(NBLK1), dim3(256), 0, stream,
                       risk, ev, tim, Pp, n, per_block);
    hipLaunchKernelGGL(k1_probe2, dim3(NBLK1), dim3(256), 0, stream,
                       risk, ev, tim, Pp2, n, per_block);
    hipLaunchKernelGGL(k1_bucket, dim3(NBLK1), dim3(256), 0, stream,
                       risk, ev, tim, S, E, Apart, n, per_block);
    hipLaunchKernelGGL(k2_partials, dim3(NBLK_SC), dim3(256), 0, stream, S, partials);
    hipLaunchKernelGGL(k3_scan_dot, dim3(NBLK_SC), dim3(1024), 0, stream, S, E, partials, B);
    hipLaunchKernelGGL(k4_final, dim3(1), dim3(256), 0, stream, Apart, B, out, 1.0f / (float)n);
}

// Round 9
// 60.757 us; speedup vs baseline: 1.8797x; 1.8797x over previous
//
#include <hip/hip_runtime.h>
#include <math.h>

// Cox partial likelihood NLL.
// loss = -(1/n) * sum_i e_i * (risk_i - log(P[time_i]))
//   where P[t] = sum_{t' <= t} S[t'],  S[t] = sum_{time_j = t} exp(risk_j)
// Decompose: A = sum_i e_i*risk_i ; B = sum_t E[t]*log(P[t]), E[t] = sum_{time_j=t} e_j
// loss = -(A - B)/n
//
// R9: COALESCED loads. R8's ablation proved the per-thread-contiguous strip
// layout was the wall (pure-load probe = 67us even L3-resident: each dwordx4
// spanned 64 cache lines -> L1/TA tag serialization). Now lane-contiguous
// float4 (16 lines/instr): thread owns 4-elem mini-strips in 4 segments of
// 256 per wave-strip of 1024; R5's proven segmented-scan run logic applied
// per segment; segment-boundary run pieces flushed via (exonerated) atomics.

#define NPAD    100352          // 98 * 1024, padded bucket count
#define NBLK_SC 98
#define NBLK1   2048
#define SENT    0x7fffffff      // sentinel time for invalid lanes

__device__ __forceinline__ void atomAddF(float* p, float v) {
    unsafeAtomicAdd(p, v);      // native global_atomic_add_f32
}

// Block reduce (up to 16 waves). Result valid in lane 0 of wave 0 only.
__device__ __forceinline__ float block_reduce_sum(float v, float* lds) {
    const int lane = threadIdx.x & 63;
    const int wid  = threadIdx.x >> 6;
    #pragma unroll
    for (int d = 32; d > 0; d >>= 1) v += __shfl_down(v, d);
    __syncthreads();
    if (lane == 0) lds[wid] = v;
    __syncthreads();
    float r = 0.f;
    if (wid == 0) {
        const int nw = (int)(blockDim.x >> 6);
        r = (lane < nw) ? lds[lane] : 0.f;
        #pragma unroll
        for (int d = 8; d > 0; d >>= 1) r += __shfl_down(r, d);
    }
    return r;
}

__global__ __launch_bounds__(256)
void k1_bucket(const float* __restrict__ risk, const float* __restrict__ ev,
               const int* __restrict__ tim,
               float* __restrict__ S, float* __restrict__ E,
               float* __restrict__ Apart, int n, int per_block) {
    __shared__ float lds[16];
    const int lane = (int)threadIdx.x & 63;
    const int wid  = (int)threadIdx.x >> 6;
    const int start = (int)blockIdx.x * per_block;
    int end = start + per_block;
    if (end > n) end = n;

    float accA = 0.f;

    for (int i0 = start; i0 < end; i0 += 4096) {      // block-iter: 4 waves x 1024
        const int sbase = i0 + wid * 1024;            // this wave's strip

        // ---- load all 4 segments up-front, fully coalesced (lane*16B) ----
        float r[4][4], w[4][4];
        int   t[4][4];
        #pragma unroll
        for (int q = 0; q < 4; ++q) {
            const int base = sbase + q * 256 + lane * 4;
            if (base + 4 <= end) {
                const float4 rr = *(const float4*)(risk + base);
                const float4 ww = *(const float4*)(ev   + base);
                const int4   tt = *(const int4*)(tim   + base);
                r[q][0]=rr.x; r[q][1]=rr.y; r[q][2]=rr.z; r[q][3]=rr.w;
                w[q][0]=ww.x; w[q][1]=ww.y; w[q][2]=ww.z; w[q][3]=ww.w;
                t[q][0]=tt.x; t[q][1]=tt.y; t[q][2]=tt.z; t[q][3]=tt.w;
            } else {
                #pragma unroll
                for (int j = 0; j < 4; ++j) {
                    const int i = base + j;
                    const bool ok = (i < end);
                    r[q][j] = ok ? risk[i] : 0.f;
                    w[q][j] = ok ? ev[i]   : 0.f;
                    t[q][j] = ok ? tim[i]  : SENT;
                }
            }
        }

        // ---- process each 256-elem segment with the proven R5 run logic ----
        #pragma unroll
        for (int q = 0; q < 4; ++q) {
            float ve[4];
            #pragma unroll
            for (int j = 0; j < 4; ++j) {
                ve[j] = __expf(r[q][j]);
                accA += w[q][j] * r[q][j];            // w==0 for invalid lanes
            }

            const int head_t = t[q][0];
            const int tail_t = t[q][3];

            // trailing-run sums (sorted => equality to tail is contiguous)
            float tsv = 0.f, tsw = 0.f;
            #pragma unroll
            for (int j = 0; j < 4; ++j) {
                if (t[q][j] == tail_t) { tsv += ve[j]; tsw += w[q][j]; }
            }

            // cross-lane segmented inclusive scan keyed on tail_t
            float Sv = tsv, Sw = tsw;
            #pragma unroll
            for (int d = 1; d < 64; d <<= 1) {
                const float ov = __shfl_up(Sv, d);
                const float ow = __shfl_up(Sw, d);
                const int   ok = __shfl_up(tail_t, d);
                if (lane >= d && ok == tail_t) { Sv += ov; Sw += ow; }
            }

            // carry into this thread's head run (exact under sortedness)
            float cv = 0.f, cw = 0.f;
            {
                const float pv = __shfl_up(Sv, 1);
                const float pw = __shfl_up(Sw, 1);
                const int   pk = __shfl_up(tail_t, 1);
                if (lane > 0 && pk == head_t) { cv = pv; cw = pw; }
            }

            // per-thread sequential run pass, flushing closed runs
            int   cur_t = head_t;
            float cur_v = cv, cur_w = cw;
            #pragma unroll
            for (int j = 0; j < 4; ++j) {
                if (t[q][j] != cur_t) {
                    if (cur_t != SENT) {
                        atomAddF(&S[cur_t], cur_v);
                        atomAddF(&E[cur_t], cur_w);
                    }
                    cur_t = t[q][j]; cur_v = 0.f; cur_w = 0.f;
                }
                cur_v += ve[j]; cur_w += w[q][j];
            }
            // trailing run: flush unless it continues into the next lane
            const int nh = __shfl_down(head_t, 1);
            if ((lane == 63 || nh != tail_t) && cur_t != SENT) {
                atomAddF(&S[cur_t], cur_v);
                atomAddF(&E[cur_t], cur_w);
            }
        }
    }

    const float tot = block_reduce_sum(accA, lds);
    if (threadIdx.x == 0) Apart[blockIdx.x] = tot;
}

// K2: per-1024-chunk partial sums of S.
__global__ __launch_bounds__(256)
void k2_partials(const float* __restrict__ S, float* __restrict__ partials) {
    __shared__ float lds[16];
    const int base = (int)blockIdx.x * 1024;
    float v = 0.f;
    for (int j = (int)threadIdx.x; j < 1024; j += 256) v += S[base + j];
    const float tot = block_reduce_sum(v, lds);
    if (threadIdx.x == 0) partials[blockIdx.x] = tot;
}

// K3: per-chunk inclusive scan of S (+offset), dot with E via log(P) -> B.
__global__ __launch_bounds__(1024)
void k3_scan_dot(const float* __restrict__ S, const float* __restrict__ E,
                 const float* __restrict__ partials, float* __restrict__ Bacc) {
    __shared__ float lds[16];
    __shared__ float wsum[16];
    __shared__ float s_off;
    const int tid  = (int)threadIdx.x;
    const int lane = tid & 63;
    const int wid  = tid >> 6;
    const int base = (int)blockIdx.x * 1024;

    float p = (tid < (int)blockIdx.x) ? partials[tid] : 0.f;
    const float off = block_reduce_sum(p, lds);
    if (tid == 0) s_off = off;
    __syncthreads();
    const float offset = s_off;

    const float x = S[base + tid];
    float s = x;
    #pragma unroll
    for (int d = 1; d < 64; d <<= 1) {
        const float o = __shfl_up(s, d);
        if (lane >= d) s += o;
    }
    if (lane == 63) wsum[wid] = s;
    __syncthreads();
    if (wid == 0) {
        float ws = (lane < 16) ? wsum[lane] : 0.f;
        #pragma unroll
        for (int d = 1; d < 16; d <<= 1) {
            const float o = __shfl_up(ws, d);
            if (lane >= d) ws += o;
        }
        if (lane < 16) wsum[lane] = ws;
    }
    __syncthreads();
    const float incl = s + (wid > 0 ? wsum[wid - 1] : 0.f);
    const float P = offset + incl;

    const float w = E[base + tid];
    const float c = (w != 0.f) ? w * __logf(P) : 0.f;
    const float tot = block_reduce_sum(c, lds);
    if (tid == 0) atomAddF(Bacc, tot);
}

// K4: reduce Apart[NBLK1], combine with B, write loss.
__global__ __launch_bounds__(256)
void k4_final(const float* __restrict__ Apart, const float* __restrict__ B,
              float* __restrict__ out, float inv_n) {
    __shared__ float lds[16];
    float v = 0.f;
    for (int j = (int)threadIdx.x; j < NBLK1; j += 256) v += Apart[j];
    const float tot = block_reduce_sum(v, lds);
    if (threadIdx.x == 0) out[0] = -(tot - B[0]) * inv_n;
}

extern "C" void kernel_launch(void* const* d_in, const int* in_sizes, int n_in,
                              void* d_out, int out_size, void* d_ws, size_t ws_size,
                              hipStream_t stream) {
    const float* risk = (const float*)d_in[0];
    const float* ev   = (const float*)d_in[1];
    const int*   tim  = (const int*)d_in[2];
    float* out = (float*)d_out;
    const int n = in_sizes[0];

    // ws (floats): S[NPAD] E[NPAD] partials[128] Apart[NBLK1] B[2]
    float* S        = (float*)d_ws;
    float* E        = S + NPAD;
    float* partials = E + NPAD;
    float* Apart    = partials + 128;
    float* B        = Apart + NBLK1;

    hipMemsetAsync(d_ws, 0, (size_t)(2 * NPAD + 128 + NBLK1 + 2) * sizeof(float), stream);

    const int win = 4096;                              // elements per block-iter
    int per_block = (n + NBLK1 - 1) / NBLK1;
    per_block = ((per_block + win - 1) / win) * win;   // 8192 for N=16.7M

    hipLaunchKernelGGL(k1_bucket, dim3(NBLK1), dim3(256), 0, stream,
                       risk, ev, tim, S, E, Apart, n, per_block);
    hipLaunchKernelGGL(k2_partials, dim3(NBLK_SC), dim3(256), 0, stream, S, partials);
    hipLaunchKernelGGL(k3_scan_dot, dim3(NBLK_SC), dim3(1024), 0, stream, S, E, partials, B);
    hipLaunchKernelGGL(k4_final, dim3(1), dim3(256), 0, stream, Apart, B, out, 1.0f / (float)n);
}